// Round 1
// baseline (280.284 us; speedup 1.0000x reference)
//
#include <hip/hip_runtime.h>

// FieldAwareFMLayer: x (bs, 40, 39, 16) fp32.
// out[n] = sum_{0<=i<=j<=38} dot(x[n,i,j,:], x[n,j+1,i,:])
// 780 pairs, each embedding is one 64B-aligned 64B line, every element of
// the input participates in exactly one product -> pure streaming read.

#define NPAIRS 780
#define ROW_FLOATS 24960      // 40*39*16
#define NTASKS (NPAIRS * 4)   // one float4 partial-dot per task

struct PairTab {
    unsigned short o0[NPAIRS];  // embedding index (f*39+j) for the j>=i side
    unsigned short o1[NPAIRS];  // embedding index for the (j+1, i) side
};

static constexpr PairTab make_tab() {
    PairTab t{};
    int p = 0;
    for (int i = 0; i < 39; ++i) {
        for (int j = i; j < 39; ++j, ++p) {
            t.o0[p] = (unsigned short)(i * 39 + j);
            t.o1[p] = (unsigned short)((j + 1) * 39 + i);
        }
    }
    return t;
}

__constant__ PairTab c_tab = make_tab();

__global__ __launch_bounds__(256) void ffm_interact_kernel(
        const float* __restrict__ x, float* __restrict__ out) {
    const int n = blockIdx.x;
    const float4* __restrict__ base4 =
        (const float4*)(x + (size_t)n * ROW_FLOATS);

    float acc = 0.0f;
    // 3120 tasks, 256 threads -> 13 grid-stride iterations (last partial).
    for (int task = threadIdx.x; task < NTASKS; task += 256) {
        const int p = task >> 2;
        const int q = task & 3;
        const float4 a = base4[(int)c_tab.o0[p] * 4 + q];
        const float4 b = base4[(int)c_tab.o1[p] * 4 + q];
        acc = fmaf(a.x, b.x, acc);
        acc = fmaf(a.y, b.y, acc);
        acc = fmaf(a.z, b.z, acc);
        acc = fmaf(a.w, b.w, acc);
    }

    // wave-64 butterfly reduce
    #pragma unroll
    for (int off = 32; off > 0; off >>= 1)
        acc += __shfl_down(acc, off, 64);

    __shared__ float wave_sum[4];
    const int lane = threadIdx.x & 63;
    const int wid  = threadIdx.x >> 6;
    if (lane == 0) wave_sum[wid] = acc;
    __syncthreads();
    if (threadIdx.x == 0)
        out[n] = wave_sum[0] + wave_sum[1] + wave_sum[2] + wave_sum[3];
}

extern "C" void kernel_launch(void* const* d_in, const int* in_sizes, int n_in,
                              void* d_out, int out_size, void* d_ws, size_t ws_size,
                              hipStream_t stream) {
    const float* x = (const float*)d_in[0];
    float* out = (float*)d_out;
    const int bs = in_sizes[0] / ROW_FLOATS;   // 2048
    ffm_interact_kernel<<<bs, 256, 0, stream>>>(x, out);
}

// Round 2
// 274.878 us; speedup vs baseline: 1.0197x; 1.0197x over previous
//
#include <hip/hip_runtime.h>

// FieldAwareFMLayer: x (bs, 40, 39, 16) fp32.
// out[n] = sum_{0<=i<=j<=38} dot(x[n,i,j,:], x[n,j+1,i,:])
//
// Pairing structure: the "a" operands are exactly the upper wedge
// {(f,c): c>=f}, the "b" operands exactly the lower wedge {(f,c): c<f}.
// Each input element participates in exactly one product -> pure streaming.
// Strategy: stage the lower wedge (780 embeddings = 48.75 KB) packed into
// LDS with contiguous-run global loads, then stream the upper wedge
// (contiguous runs) and dot against the LDS partner. All HBM traffic is
// contiguous and exactly-once.

#define NF 40
#define NC 39
#define ED 16
#define NPAIRS 780
#define ROW_FLOATS (NF * NC * ED)   // 24960 floats = 99840 B per batch row
#define NTASKS (NPAIRS * 4)         // one float4 partial-dot per task = 3120
#define NTHREADS 512

struct Tables {
    unsigned short a_glob[NPAIRS];  // pair p -> global embedding idx of a=(i,j)
    unsigned short b_slot[NPAIRS];  // pair p -> packed LDS slot of b=(j+1,i)
    unsigned short b_glob[NPAIRS];  // packed slot s -> global embedding idx of b
};

static constexpr Tables make_tables() {
    Tables t{};
    int p = 0;
    for (int i = 0; i < NC; ++i)
        for (int j = i; j < NC; ++j, ++p) {
            t.a_glob[p] = (unsigned short)(i * NC + j);
            t.b_slot[p] = (unsigned short)((j + 1) * j / 2 + i);
        }
    // lower wedge (g,c), c<g, packed at slot g*(g-1)/2 + c
    for (int g = 1; g < NF; ++g)
        for (int c = 0; c < g; ++c)
            t.b_glob[g * (g - 1) / 2 + c] = (unsigned short)(g * NC + c);
    return t;
}

__constant__ Tables c_tab = make_tables();

__global__ __launch_bounds__(NTHREADS) void ffm_interact_kernel(
        const float* __restrict__ x, float* __restrict__ out) {
    __shared__ float ldsb[NPAIRS * ED];       // 49920 B -> 3 blocks/CU
    const int n = blockIdx.x;
    const int tid = threadIdx.x;
    const float4* __restrict__ base4 =
        (const float4*)(x + (size_t)n * ROW_FLOATS);
    float4* lds4 = (float4*)ldsb;

    // Phase 1: stage lower wedge into LDS (packed, contiguous writes).
    #pragma unroll
    for (int t = tid; t < NTASKS; t += NTHREADS) {
        const int s = t >> 2;
        const int q = t & 3;
        lds4[s * 4 + q] = base4[(int)c_tab.b_glob[s] * 4 + q];
    }
    __syncthreads();

    // Phase 2: stream upper wedge from global, dot against LDS partner.
    float acc = 0.0f;
    #pragma unroll
    for (int t = tid; t < NTASKS; t += NTHREADS) {
        const int p = t >> 2;
        const int q = t & 3;
        const float4 a = base4[(int)c_tab.a_glob[p] * 4 + q];
        const float4 b = lds4[(int)c_tab.b_slot[p] * 4 + q];
        acc = fmaf(a.x, b.x, acc);
        acc = fmaf(a.y, b.y, acc);
        acc = fmaf(a.z, b.z, acc);
        acc = fmaf(a.w, b.w, acc);
    }

    // wave-64 butterfly reduce, then cross-wave via LDS
    #pragma unroll
    for (int off = 32; off > 0; off >>= 1)
        acc += __shfl_down(acc, off, 64);

    __shared__ float wave_sum[NTHREADS / 64];
    const int lane = threadIdx.x & 63;
    const int wid  = threadIdx.x >> 6;
    if (lane == 0) wave_sum[wid] = acc;
    __syncthreads();
    if (tid == 0) {
        float s = 0.0f;
        #pragma unroll
        for (int w = 0; w < NTHREADS / 64; ++w) s += wave_sum[w];
        out[n] = s;
    }
}

extern "C" void kernel_launch(void* const* d_in, const int* in_sizes, int n_in,
                              void* d_out, int out_size, void* d_ws, size_t ws_size,
                              hipStream_t stream) {
    const float* x = (const float*)d_in[0];
    float* out = (float*)d_out;
    const int bs = in_sizes[0] / ROW_FLOATS;   // 2048
    ffm_interact_kernel<<<bs, NTHREADS, 0, stream>>>(x, out);
}

// Round 3
// 257.006 us; speedup vs baseline: 1.0906x; 1.0695x over previous
//
#include <hip/hip_runtime.h>

// FieldAwareFMLayer: x (bs, 40, 39, 16) fp32.
// out[n] = sum_{0<=i<=j<=38} dot(x[n,i,j,:], x[n,j+1,i,:])
//
// Every input element participates in exactly one product -> pure streaming,
// 204.5 MB read total => HBM-bound, roofline ~33 us.
// This version attacks memory-level parallelism: one packed u32 index load
// per task, then 14 independent float4 global loads issued back-to-back per
// thread (fully unrolled, batched), then the FMAs. No LDS staging (R2 showed
// DRAM pattern was not the limiter), non-temporal loads (zero reuse).

#define NF 40
#define NC 39
#define ED 16
#define NPAIRS 780
#define ROW_FLOATS (NF * NC * ED)     // 24960 floats per batch row
#define NTASKS (NPAIRS * 4)           // one float4 partial-dot per task = 3120
#define NTH 512
#define TRIPS ((NTASKS + NTH - 1) / NTH)   // 7 (last trip masked for tid>=48... clamped)

typedef float f32x4 __attribute__((ext_vector_type(4)));

struct PairPack { unsigned int pk[NPAIRS]; };

static constexpr PairPack make_pk() {
    PairPack t{};
    int p = 0;
    for (int i = 0; i < NC; ++i)
        for (int j = i; j < NC; ++j, ++p)
            t.pk[p] = (unsigned)(i * NC + j)            // a = (i, j)
                    | ((unsigned)((j + 1) * NC + i) << 16);  // b = (j+1, i)
    return t;
}

__constant__ PairPack c_tab = make_pk();

__global__ __launch_bounds__(NTH) void ffm_interact_kernel(
        const float* __restrict__ x, float* __restrict__ out) {
    const int n = blockIdx.x;
    const int tid = threadIdx.x;
    const int q = tid & 3;            // quad within embedding (constant across trips)
    const f32x4* __restrict__ base4 =
        (const f32x4*)(x + (size_t)n * ROW_FLOATS);

    // 1) all index loads (small, constant-cached)
    unsigned idx[TRIPS];
    #pragma unroll
    for (int k = 0; k < TRIPS; ++k) {
        int p = (tid + k * NTH) >> 2;
        idx[k] = c_tab.pk[p < NPAIRS ? p : 0];   // clamp tail, masked below
    }

    // 2) all global loads, batched -> 14 outstanding 16B loads per thread
    f32x4 av[TRIPS], bv[TRIPS];
    #pragma unroll
    for (int k = 0; k < TRIPS; ++k)
        av[k] = __builtin_nontemporal_load(&base4[(int)(idx[k] & 0xffffu) * 4 + q]);
    #pragma unroll
    for (int k = 0; k < TRIPS; ++k)
        bv[k] = __builtin_nontemporal_load(&base4[(int)(idx[k] >> 16) * 4 + q]);

    // 3) FMAs, tail-masked
    float acc = 0.0f;
    #pragma unroll
    for (int k = 0; k < TRIPS; ++k) {
        const float m = ((tid + k * NTH) < NTASKS) ? 1.0f : 0.0f;
        acc = fmaf(m * av[k][0], bv[k][0], acc);
        acc = fmaf(m * av[k][1], bv[k][1], acc);
        acc = fmaf(m * av[k][2], bv[k][2], acc);
        acc = fmaf(m * av[k][3], bv[k][3], acc);
    }

    // wave-64 reduce, then cross-wave via LDS
    #pragma unroll
    for (int off = 32; off > 0; off >>= 1)
        acc += __shfl_down(acc, off, 64);

    __shared__ float wave_sum[NTH / 64];
    if ((tid & 63) == 0) wave_sum[tid >> 6] = acc;
    __syncthreads();
    if (tid == 0) {
        float s = 0.0f;
        #pragma unroll
        for (int w = 0; w < NTH / 64; ++w) s += wave_sum[w];
        out[n] = s;
    }
}

extern "C" void kernel_launch(void* const* d_in, const int* in_sizes, int n_in,
                              void* d_out, int out_size, void* d_ws, size_t ws_size,
                              hipStream_t stream) {
    const float* x = (const float*)d_in[0];
    float* out = (float*)d_out;
    const int bs = in_sizes[0] / ROW_FLOATS;   // 2048
    ffm_interact_kernel<<<bs, NTH, 0, stream>>>(x, out);
}

// Round 4
// 254.901 us; speedup vs baseline: 1.0996x; 1.0083x over previous
//
#include <hip/hip_runtime.h>

// FieldAwareFMLayer: x (bs, 40, 39, 16) fp32.
// out[n] = sum_{0<=i<=j<=38} dot(x[n,i,j,:], x[n,j+1,i,:])
//
// Every input element participates in exactly one product -> pure streaming,
// 204.5 MB read => HBM-bound, roofline ~30-33 us.
// R3 batched 14 independent float4 loads per thread (MLP fix, -18 us).
// R4: replace the constant-table index loads with pure-VALU triangular
// decode (indices depend only on threadIdx.x), so no memory op gates the
// address computation -- all 14 streaming loads issue at wave start.

#define NF 40
#define NC 39
#define ED 16
#define NPAIRS 780
#define ROW_FLOATS (NF * NC * ED)     // 24960 floats per batch row
#define NTASKS (NPAIRS * 4)           // one float4 partial-dot per task = 3120
#define NTH 512
#define TRIPS ((NTASKS + NTH - 1) / NTH)   // 7

typedef float f32x4 __attribute__((ext_vector_type(4)));

__global__ __launch_bounds__(NTH) void ffm_interact_kernel(
        const float* __restrict__ x, float* __restrict__ out) {
    const int n = blockIdx.x;
    const int tid = threadIdx.x;
    const int q = tid & 3;            // quad within embedding
    const int p0 = tid >> 2;          // p_k = p0 + 128*k  (512k>>2, no carry)
    const f32x4* __restrict__ base4 =
        (const f32x4*)(x + (size_t)n * ROW_FLOATS);

    // 1) arithmetic index decode (no memory dependency):
    //    pair p -> (i,j): i = floor((79 - sqrt(6241 - 8p))/2), guarded;
    //    S(i) = 39i - i(i-1)/2; j = i + p - S(i).
    int aoff[TRIPS], boff[TRIPS];
    #pragma unroll
    for (int k = 0; k < TRIPS; ++k) {
        int p = p0 + 128 * k;
        p = p < NPAIRS ? p : (NPAIRS - 1);       // clamp tail (masked below)
        const float disc = 6241.0f - 8.0f * (float)p;
        int i = (int)((79.0f - __builtin_sqrtf(disc)) * 0.5f);
        int Si = 39 * i - ((i * (i - 1)) >> 1);
        if (p < Si) { --i; Si = 39 * i - ((i * (i - 1)) >> 1); }
        else { const int Si1 = Si + (NC - i); if (p >= Si1) { ++i; Si = Si1; } }
        const int j = i + (p - Si);
        aoff[k] = (i * NC + j) * 4 + q;          // a = (i, j)
        boff[k] = ((j + 1) * NC + i) * 4 + q;    // b = (j+1, i)
    }

    // 2) all global loads batched -> 14 outstanding 16B loads per thread
    f32x4 av[TRIPS], bv[TRIPS];
    #pragma unroll
    for (int k = 0; k < TRIPS; ++k)
        av[k] = __builtin_nontemporal_load(&base4[aoff[k]]);
    #pragma unroll
    for (int k = 0; k < TRIPS; ++k)
        bv[k] = __builtin_nontemporal_load(&base4[boff[k]]);

    // 3) FMAs, tail-masked
    float acc = 0.0f;
    #pragma unroll
    for (int k = 0; k < TRIPS; ++k) {
        const float m = ((tid + k * NTH) < NTASKS) ? 1.0f : 0.0f;
        acc = fmaf(m * av[k][0], bv[k][0], acc);
        acc = fmaf(m * av[k][1], bv[k][1], acc);
        acc = fmaf(m * av[k][2], bv[k][2], acc);
        acc = fmaf(m * av[k][3], bv[k][3], acc);
    }

    // wave-64 reduce, then cross-wave via LDS
    #pragma unroll
    for (int off = 32; off > 0; off >>= 1)
        acc += __shfl_down(acc, off, 64);

    __shared__ float wave_sum[NTH / 64];
    if ((tid & 63) == 0) wave_sum[tid >> 6] = acc;
    __syncthreads();
    if (tid == 0) {
        float s = 0.0f;
        #pragma unroll
        for (int w = 0; w < NTH / 64; ++w) s += wave_sum[w];
        out[n] = s;
    }
}

extern "C" void kernel_launch(void* const* d_in, const int* in_sizes, int n_in,
                              void* d_out, int out_size, void* d_ws, size_t ws_size,
                              hipStream_t stream) {
    const float* x = (const float*)d_in[0];
    float* out = (float*)d_out;
    const int bs = in_sizes[0] / ROW_FLOATS;   // 2048
    ffm_interact_kernel<<<bs, NTH, 0, stream>>>(x, out);
}